// Round 20
// baseline (225.760 us; speedup 1.0000x reference)
//
#include <hip/hip_runtime.h>

// ---------------------------------------------------------------------------
// ModulatedConvBlock on MI355X (gfx950) — round 20
// Base = R18 (measured best, 218.3us). ONE change: the demod stage is folded
// into k_conv's prologue — computed under the prologue's vmcnt(0) staging
// stall (free latency), partials via LDS, rsqrt into dem_s[128]; epilogue
// reads LDS. k_pre2 becomes a pure 528-block upsample (R18 body verbatim).
// Removes 1024 demod blocks + demod global traffic from the secondary chain.
// ---------------------------------------------------------------------------

typedef short bf16x8 __attribute__((ext_vector_type(8)));
typedef short short8v __attribute__((ext_vector_type(8)));
typedef float f32x16 __attribute__((ext_vector_type(16)));

// workspace layout (bytes)
#define WS_STYLE 0            // [8][512] f32
#define WS_WSQ   32768        // [512][512] f32
#define WS_WPACK 1081344      // [tap9][cc16][o512][sp4][8] bf16 (4718592 B)
#define WS_XM    5799936      // [8][66][66][512] bf16 (35684352 B)
#define WS_PART  41484288     // [4 slice][8 b][3 c][64 h][64 w] f32 (1572864 B)

__device__ __forceinline__ short f2bf(float f) {
  unsigned u = __float_as_uint(f);
  u += 0x7FFFu + ((u >> 16) & 1u);   // round-to-nearest-even
  return (short)(u >> 16);
}

__device__ __forceinline__ void gld16(const short* g, char* l) {
  __builtin_amdgcn_global_load_lds((const __attribute__((address_space(1))) void*)g,
                                   (__attribute__((address_space(3))) void*)l,
                                   16, 0, 0);
}

// ---------------- pre1: style (blk 0..7) + wsq (8..1031) + packw (1032..) ---
__global__ void k_pre1(const float* __restrict__ sb, const float* __restrict__ aw,
                       const float* __restrict__ ab, const float* __restrict__ cw,
                       float* __restrict__ style, float* __restrict__ wsq,
                       short* __restrict__ wpk) {
  __shared__ float s_sb[512];
  int bid = blockIdx.x, tid = threadIdx.x;
  if (bid < 8) {
    int b = bid;
    for (int i = tid; i < 512; i += 256) s_sb[i] = sb[b * 512 + i] * 0.0625f;
    __syncthreads();
    for (int i = tid; i < 512; i += 256) {
      const float4* wrow = (const float4*)(aw + (size_t)i * 512);
      float acc = 0.f;
      #pragma unroll 4
      for (int s4 = 0; s4 < 128; ++s4) {
        float4 w4 = wrow[s4];
        float4 sv = *(const float4*)(s_sb + s4 * 4);
        acc += w4.x * sv.x + w4.y * sv.y + w4.z * sv.z + w4.w * sv.w;
      }
      style[b * 512 + i] = acc + ab[i] + 1.0f;
    }
  } else if (bid < 1032) {
    int idx = (bid - 8) * 256 + tid;            // o*512+i
    const float* p = cw + (size_t)idx * 9;
    float s = 0.f;
    #pragma unroll
    for (int j = 0; j < 9; ++j) s += p[j] * p[j];
    wsq[idx] = s;
  } else {
    // wpk[tap][cc][o][sp][j] = cw[o][ cc*32 + (sp^((o>>1)&3))*8 + j ][tap]
    int unit = (bid - 1032) * 256 + tid;        // < 294912
    int s = unit >> 11;
    int rem = unit & 2047;
    int o = rem >> 2, sp = rem & 3;
    int tap = s >> 4, cc = s & 15;
    int i0 = cc * 32 + ((sp ^ ((o >> 1) & 3)) << 3);
    const float* src = cw + ((size_t)o * 512 + i0) * 9 + tap;
    short8v v;
    #pragma unroll
    for (int j = 0; j < 8; ++j) v[j] = f2bf(src[j * 9]);
    *(short8v*)(wpk + (size_t)unit * 8) = v;
  }
}

// ---------------- upsample 2x bilinear (half-pixel) + modulate, NHWC pad ----
__global__ void k_upsm(const float* __restrict__ x, const float* __restrict__ style,
                       short* __restrict__ xm) {
  __shared__ float xt[2][64][33];
  int bid = blockIdx.x, tid = threadIdx.x;
  int b = bid / 66, hp = bid % 66;
  short* xmp = xm + ((size_t)b * 66 + hp) * 66 * 512;
  if (hp == 0 || hp == 65) {
    short8v z = {0, 0, 0, 0, 0, 0, 0, 0};
    for (int u = tid; u < 66 * 512 / 8; u += 256) ((short8v*)xmp)[u] = z;
    return;
  }
  int h = hp - 1;
  int j0 = (h >> 1) - 1 + (h & 1);
  float fj = (h & 1) ? 0.25f : 0.75f;
  int j0c = j0 < 0 ? 0 : j0;
  int j1c = j0 + 1 > 31 ? 31 : j0 + 1;
  int ccc = tid & 63;
  int wsub = tid >> 6;
  for (int c0 = 0; c0 < 512; c0 += 64) {
    __syncthreads();
    #pragma unroll 4
    for (int k = 0; k < 16; ++k) {
      int idx = k * 256 + tid;
      int ii = idx & 31, cc = (idx >> 5) & 63, jj = idx >> 11;
      xt[jj][cc][ii] = x[(((size_t)b * 512 + c0 + cc) * 32 + (jj ? j1c : j0c)) * 32 + ii];
    }
    __syncthreads();
    float sstyle = style[b * 512 + c0 + ccc];
    #pragma unroll 4
    for (int wk = 0; wk < 16; ++wk) {
      int w = wk * 4 + wsub;
      int i0 = (w >> 1) - 1 + (w & 1);
      float fi = (w & 1) ? 0.25f : 0.75f;
      int i0c = i0 < 0 ? 0 : i0;
      int i1c = i0 + 1 > 31 ? 31 : i0 + 1;
      float v0 = xt[0][ccc][i0c] * (1.f - fi) + xt[0][ccc][i1c] * fi;
      float v1 = xt[1][ccc][i0c] * (1.f - fi) + xt[1][ccc][i1c] * fi;
      float v = (v0 * (1.f - fj) + v1 * fj) * sstyle;
      xmp[(size_t)(w + 1) * 512 + c0 + ccc] = f2bf(v);
    }
    if (wsub == 0) {
      xmp[c0 + ccc] = 0;
      xmp[(size_t)65 * 512 + c0 + ccc] = 0;
    }
  }
}

// ---------------- main conv: 2 blocks/CU, demod in prologue, fused rgb ------
// grid 512; T1 XCD swizzle: 4 coq blocks of one (hq,b) -> same XCD L2.
// wave: 128 cout (coq*128..) x row(hq*4+wsrow) x 64 w
__global__ __launch_bounds__(256, 2) void k_conv(
    const short* __restrict__ xm, const short* __restrict__ wpk,
    const float* __restrict__ wsq, const float* __restrict__ style,
    const float* __restrict__ convb,
    const float* __restrict__ nscal, const float* __restrict__ noise,
    const float* __restrict__ t, const float* __restrict__ prelu_a,
    const float* __restrict__ ow, float* __restrict__ part,
    float* __restrict__ y) {
  __shared__ char WTs[6][8192];    // ring: parity*3+slab, 128co x 4sp x 16B
  __shared__ char XMb[25344];      // single: [6 r][66 wp][4 slot]x16B
  __shared__ float dem_p[256];     // demod partials
  __shared__ float dem_s[128];     // demod for this block's 128 couts

  int tid = threadIdx.x;
  int bid = blockIdx.x;
  int xcd = bid & 7, q = bid >> 3;
  int coq = q & 3, ghi = q >> 2;
  int g5 = ghi * 8 + xcd;          // 0..127
  int hq = g5 & 15, b = g5 >> 4;
  int wsrow = tid >> 6, lane = tid & 63;
  int l31 = lane & 31, lg = lane >> 5;

  const short* xb = xm + ((size_t)b * 66 + hq * 4) * 66 * 512;
  const short* wpkq = wpk + (size_t)coq * 128 * 32;   // this block's 128 couts
  int wb0 = (l31 << 6) + ((lg ^ ((l31 >> 1) & 3)) << 4);

  // xm staging units: u = k*256+tid (k=0..5) + tail u=1536+tid (tid<48)
  int off0, off1, off2, off3, off4, off5, off6;
  int d0, d1, d2, d3, d4, d5, d6;
  {
    int u, r, rem, wp, sp;
    u = tid;        r = u / 264; rem = u - r * 264; wp = rem >> 2; sp = rem & 3;
    off0 = (r * 66 + wp) * 512 + ((sp ^ ((wp >> 1) & 3)) << 3); d0 = u * 16;
    u = 256 + tid;  r = u / 264; rem = u - r * 264; wp = rem >> 2; sp = rem & 3;
    off1 = (r * 66 + wp) * 512 + ((sp ^ ((wp >> 1) & 3)) << 3); d1 = u * 16;
    u = 512 + tid;  r = u / 264; rem = u - r * 264; wp = rem >> 2; sp = rem & 3;
    off2 = (r * 66 + wp) * 512 + ((sp ^ ((wp >> 1) & 3)) << 3); d2 = u * 16;
    u = 768 + tid;  r = u / 264; rem = u - r * 264; wp = rem >> 2; sp = rem & 3;
    off3 = (r * 66 + wp) * 512 + ((sp ^ ((wp >> 1) & 3)) << 3); d3 = u * 16;
    u = 1024 + tid; r = u / 264; rem = u - r * 264; wp = rem >> 2; sp = rem & 3;
    off4 = (r * 66 + wp) * 512 + ((sp ^ ((wp >> 1) & 3)) << 3); d4 = u * 16;
    u = 1280 + tid; r = u / 264; rem = u - r * 264; wp = rem >> 2; sp = rem & 3;
    off5 = (r * 66 + wp) * 512 + ((sp ^ ((wp >> 1) & 3)) << 3); d5 = u * 16;
    u = 1536 + (tid & 63); if (u > 1583) u = 1583;   // only tid<48 uses it
    r = u / 264; rem = u - r * 264; wp = rem >> 2; sp = rem & 3;
    off6 = (r * 66 + wp) * 512 + ((sp ^ ((wp >> 1) & 3)) << 3); d6 = u * 16;
  }

  // ---- prologue: issue XM(cc0) + WT staging ----
  gld16(xb + off0, XMb + d0);
  gld16(xb + off1, XMb + d1);
  gld16(xb + off2, XMb + d2);
  gld16(xb + off3, XMb + d3);
  gld16(xb + off4, XMb + d4);
  gld16(xb + off5, XMb + d5);
  if (tid < 48) gld16(xb + off6, XMb + d6);
  #pragma unroll
  for (int j = 0; j < 3; ++j) {
    const short* ws = wpkq + (size_t)(j * 16) * 16384;   // tap j, cc0
    gld16(ws + tid * 8, WTs[j] + tid * 16);
    gld16(ws + (256 + tid) * 8, WTs[j] + (256 + tid) * 16);
  }

  // ---- demod partials, computed under the staging stall (free latency) ----
  {
    int o_loc = tid & 127, ih = tid >> 7;
    const float4* wr4 = (const float4*)(wsq + ((size_t)(coq * 128 + o_loc)) * 512 + ih * 256);
    const float4* sr4 = (const float4*)(style + (size_t)b * 512 + ih * 256);
    float sum = 0.f;
    #pragma unroll 8
    for (int i = 0; i < 64; ++i) {
      float4 w4 = wr4[i];
      float4 s4 = sr4[i];
      sum += w4.x * s4.x * s4.x + w4.y * s4.y * s4.y
           + w4.z * s4.z * s4.z + w4.w * s4.w * s4.w;
    }
    dem_p[tid] = sum;
  }

  f32x16 zf = {0,0,0,0,0,0,0,0,0,0,0,0,0,0,0,0};
  f32x16 acc[4][2];
  #pragma unroll
  for (int i = 0; i < 4; ++i) { acc[i][0] = zf; acc[i][1] = zf; }

  asm volatile("s_waitcnt vmcnt(0) lgkmcnt(0)" ::: "memory");
  __builtin_amdgcn_s_barrier();
  if (tid < 128) dem_s[tid] = rsqrtf(dem_p[tid] + dem_p[128 + tid] + 1e-8f);
  __builtin_amdgcn_sched_barrier(0);

  short8v xr0, xr1, xr2, xr3, xr4, xr5, xr6;

  #pragma unroll 1
  for (int cc = 0; cc < 16; ++cc) {
    #pragma unroll
    for (int krow = 0; krow < 3; ++krow) {
      int g = cc * 3 + krow;
      const char* WTc = (const char*)WTs + (size_t)((g & 1) * 3) * 8192;
      char* WTn = (char*)WTs + (size_t)(((g + 1) & 1) * 3) * 8192;

      // A. stage next phase's 3 weight slabs (6 gld16, uniform)
      if (g < 47) {
        int nkrow = (krow < 2) ? krow + 1 : 0;
        int ncc = (krow < 2) ? cc : cc + 1;
        #pragma unroll
        for (int j = 0; j < 3; ++j) {
          const short* ws = wpkq + (size_t)((nkrow * 3 + j) * 16 + ncc) * 16384;
          gld16(ws + tid * 8, WTn + j * 8192 + tid * 16);
          gld16(ws + (256 + tid) * 8, WTn + j * 8192 + (256 + tid) * 16);
        }
      }
      // B. reg-load xm for cc+1 at krow2 (written at the cc boundary)
      if (krow == 2 && cc < 15) {
        const short* xs = xb + (cc + 1) * 32;
        xr0 = *(const short8v*)(xs + off0);
        xr1 = *(const short8v*)(xs + off1);
        xr2 = *(const short8v*)(xs + off2);
        xr3 = *(const short8v*)(xs + off3);
        xr4 = *(const short8v*)(xs + off4);
        xr5 = *(const short8v*)(xs + off5);
        if (tid < 48) xr6 = *(const short8v*)(xs + off6);
      }

      // C. compute 3 taps (no barriers between — compiler interleaves)
      #pragma unroll
      for (int j = 0; j < 3; ++j) {
        const char* Wp = WTc + j * 8192;
        bf16x8 wf0[4], wf1[4];
        #pragma unroll
        for (int cf = 0; cf < 4; ++cf) {
          wf0[cf] = *(const bf16x8*)(Wp + (wb0 + cf * 2048));
          wf1[cf] = *(const bf16x8*)(Wp + ((wb0 + cf * 2048) ^ 32));
        }
        int a = l31 + j;            // kw = j
        int xo = ((wsrow + krow) * 66 + a) * 64 + ((lg ^ ((a >> 1) & 3)) << 4);
        bf16x8 xf00 = *(const bf16x8*)(XMb + xo);
        bf16x8 xf01 = *(const bf16x8*)(XMb + xo + 2048);
        bf16x8 xf10 = *(const bf16x8*)(XMb + (xo ^ 32));
        bf16x8 xf11 = *(const bf16x8*)(XMb + ((xo ^ 32) + 2048));

        #pragma unroll
        for (int cf = 0; cf < 4; ++cf) {
          acc[cf][0] = __builtin_amdgcn_mfma_f32_32x32x16_bf16(wf0[cf], xf00, acc[cf][0], 0, 0, 0);
          acc[cf][1] = __builtin_amdgcn_mfma_f32_32x32x16_bf16(wf0[cf], xf01, acc[cf][1], 0, 0, 0);
        }
        #pragma unroll
        for (int cf = 0; cf < 4; ++cf) {
          acc[cf][0] = __builtin_amdgcn_mfma_f32_32x32x16_bf16(wf1[cf], xf10, acc[cf][0], 0, 0, 0);
          acc[cf][1] = __builtin_amdgcn_mfma_f32_32x32x16_bf16(wf1[cf], xf11, acc[cf][1], 0, 0, 0);
        }
      }

      // D. phase end
      if (krow < 2) {
        asm volatile("s_waitcnt vmcnt(0)" ::: "memory");
        __builtin_amdgcn_s_barrier();
        __builtin_amdgcn_sched_barrier(0);
      } else {
        // cc boundary: all waves done reading XM; swap contents in place
        asm volatile("s_waitcnt vmcnt(0) lgkmcnt(0)" ::: "memory");
        __builtin_amdgcn_s_barrier();
        if (cc < 15) {
          *(short8v*)(XMb + d0) = xr0;
          *(short8v*)(XMb + d1) = xr1;
          *(short8v*)(XMb + d2) = xr2;
          *(short8v*)(XMb + d3) = xr3;
          *(short8v*)(XMb + d4) = xr4;
          *(short8v*)(XMb + d5) = xr5;
          if (tid < 48) *(short8v*)(XMb + d6) = xr6;
        }
        asm volatile("s_waitcnt lgkmcnt(0)" ::: "memory");
        __builtin_amdgcn_s_barrier();
        __builtin_amdgcn_sched_barrier(0);
      }
    }
  }

  // ---- epilogue: demod + bias + noise + prelu + (y+t)/sqrt2 + rgb partials --
  float pa = prelu_a[0];
  const float inv_r2 = 1.0f / 1.41421f;
  int h = hq * 4 + wsrow;
  float nz0 = noise[((size_t)b * 64 + h) * 64 + l31];
  float nz1 = noise[((size_t)b * 64 + h) * 64 + 32 + l31];
  float pr[3][2] = {{0.f, 0.f}, {0.f, 0.f}, {0.f, 0.f}};   // [c][sf]
  #pragma unroll
  for (int cf = 0; cf < 4; ++cf) {
    #pragma unroll
    for (int reg = 0; reg < 16; ++reg) {
      int orow = (reg & 3) + 8 * (reg >> 2) + 4 * lg;
      int o = coq * 128 + cf * 32 + orow;
      float dm = dem_s[cf * 32 + orow];
      float cb = convb[o];
      float ns = nscal[o];
      float w0 = ow[o], w1 = ow[512 + o], w2 = ow[1024 + o];
      #pragma unroll
      for (int sf = 0; sf < 2; ++sf) {
        int w = sf * 32 + l31;
        float v = acc[cf][sf][reg];
        v = v * dm + cb + ns * (sf ? nz1 : nz0);
        v = (v >= 0.f) ? v : pa * v;
        size_t oi = (((size_t)b * 512 + o) * 64 + h) * 64 + w;
        v = (v + t[oi]) * inv_r2;
        y[oi] = v;
        pr[0][sf] += v * w0;
        pr[1][sf] += v * w1;
        pr[2][sf] += v * w2;
      }
    }
  }
  #pragma unroll
  for (int c = 0; c < 3; ++c) {
    #pragma unroll
    for (int sf = 0; sf < 2; ++sf)
      pr[c][sf] += __shfl_down(pr[c][sf], 32);
  }
  if (lane < 32) {
    int slice = coq;
    float* pp = part + (((size_t)(slice * 8 + b) * 3) * 64 + h) * 64;
    #pragma unroll
    for (int c = 0; c < 3; ++c) {
      #pragma unroll
      for (int sf = 0; sf < 2; ++sf)
        pp[(size_t)c * 4096 + sf * 32 + l31] = pr[c][sf];
    }
  }
}

// ---------------- rgb finish: sum 4 slices + scale + bias + clamp -----------
__global__ void k_rgbfin(const float* __restrict__ part, const float* __restrict__ ob,
                         float* __restrict__ out) {
  int idx = blockIdx.x * 256 + threadIdx.x;   // over [b][3][64][64] = 98304
  int c = (idx / 4096) % 3;
  float s = part[idx] + part[98304 + idx] + part[196608 + idx] + part[294912 + idx];
  s = s * 0.0625f + ob[c];
  s = fminf(fmaxf(s, 0.f), 1.f);
  out[idx] = s;
}

extern "C" void kernel_launch(void* const* d_in, const int* in_sizes, int n_in,
                              void* d_out, int out_size, void* d_ws, size_t ws_size,
                              hipStream_t stream) {
  const float* x     = (const float*)d_in[0];
  const float* sb    = (const float*)d_in[1];
  const float* noise = (const float*)d_in[2];
  const float* t     = (const float*)d_in[3];
  const float* aw    = (const float*)d_in[4];
  const float* ab    = (const float*)d_in[5];
  const float* cw    = (const float*)d_in[6];
  const float* cb    = (const float*)d_in[7];
  const float* pa    = (const float*)d_in[8];
  const float* ns    = (const float*)d_in[9];
  const float* ow    = (const float*)d_in[10];
  const float* ob    = (const float*)d_in[11];
  char* ws = (char*)d_ws;
  float* style = (float*)(ws + WS_STYLE);
  float* wsq   = (float*)(ws + WS_WSQ);
  short* wpk   = (short*)(ws + WS_WPACK);
  short* xmw   = (short*)(ws + WS_XM);
  float* part  = (float*)(ws + WS_PART);
  float* y   = (float*)d_out;
  float* out = y + 16777216;

  k_pre1<<<2184, 256, 0, stream>>>(sb, aw, ab, cw, style, wsq, wpk);
  k_upsm<<<528, 256, 0, stream>>>(x, style, xmw);
  k_conv<<<512, 256, 0, stream>>>(xmw, wpk, wsq, style, cb, ns, noise, t, pa, ow, part, y);
  k_rgbfin<<<384, 256, 0, stream>>>(part, ob, out);
}

// Round 21
// 216.777 us; speedup vs baseline: 1.0414x; 1.0414x over previous
//
#include <hip/hip_runtime.h>

// ---------------------------------------------------------------------------
// ModulatedConvBlock on MI355X (gfx950) — round 21 (FINAL = R18, measured best)
// Conv: bf16 MFMA implicit GEMM, 3-tap mega-phases (48 phases, 1 barrier each),
// 2 blocks/CU (grid 512 = 4coq x 16hq x 8b, 256 thr), wave = 128co x 64sp,
// WT ring[6] 8KB slabs staged 1 phase ahead (T3/T4), xm single-buffered with
// reg-staged next-cc (T14), XOR bank swizzle both operands, T1 XCD swizzle
// (4 coq blocks of one xm tile -> same XCD L2), toRGB partials fused into the
// conv epilogue. Secondary: pre1 (style+wsq+packw) + pre2 (demod+upsample).
// Measured: 218.3us total; k_conv 170us / 41% MfmaUtil / FETCH 80MB.
// ---------------------------------------------------------------------------

typedef short bf16x8 __attribute__((ext_vector_type(8)));
typedef short short8v __attribute__((ext_vector_type(8)));
typedef float f32x16 __attribute__((ext_vector_type(16)));

// workspace layout (bytes)
#define WS_STYLE 0            // [8][512] f32
#define WS_DEMOD 16384        // [8][512] f32
#define WS_WSQ   32768        // [512][512] f32
#define WS_WPACK 1081344      // [tap9][cc16][o512][sp4][8] bf16 (4718592 B)
#define WS_XM    5799936      // [8][66][66][512] bf16 (35684352 B)
#define WS_PART  41484288     // [4 slice][8 b][3 c][64 h][64 w] f32 (1572864 B)

__device__ __forceinline__ short f2bf(float f) {
  unsigned u = __float_as_uint(f);
  u += 0x7FFFu + ((u >> 16) & 1u);   // round-to-nearest-even
  return (short)(u >> 16);
}

__device__ __forceinline__ void gld16(const short* g, char* l) {
  __builtin_amdgcn_global_load_lds((const __attribute__((address_space(1))) void*)g,
                                   (__attribute__((address_space(3))) void*)l,
                                   16, 0, 0);
}

// ---------------- pre1: style (blk 0..7) + wsq (8..1031) + packw (1032..) ---
__global__ void k_pre1(const float* __restrict__ sb, const float* __restrict__ aw,
                       const float* __restrict__ ab, const float* __restrict__ cw,
                       float* __restrict__ style, float* __restrict__ wsq,
                       short* __restrict__ wpk) {
  __shared__ float s_sb[512];
  int bid = blockIdx.x, tid = threadIdx.x;
  if (bid < 8) {
    int b = bid;
    for (int i = tid; i < 512; i += 256) s_sb[i] = sb[b * 512 + i] * 0.0625f;
    __syncthreads();
    for (int i = tid; i < 512; i += 256) {
      const float4* wrow = (const float4*)(aw + (size_t)i * 512);
      float acc = 0.f;
      #pragma unroll 4
      for (int s4 = 0; s4 < 128; ++s4) {
        float4 w4 = wrow[s4];
        float4 sv = *(const float4*)(s_sb + s4 * 4);
        acc += w4.x * sv.x + w4.y * sv.y + w4.z * sv.z + w4.w * sv.w;
      }
      style[b * 512 + i] = acc + ab[i] + 1.0f;
    }
  } else if (bid < 1032) {
    int idx = (bid - 8) * 256 + tid;            // o*512+i
    const float* p = cw + (size_t)idx * 9;
    float s = 0.f;
    #pragma unroll
    for (int j = 0; j < 9; ++j) s += p[j] * p[j];
    wsq[idx] = s;
  } else {
    // wpk[tap][cc][o][sp][j] = cw[o][ cc*32 + (sp^((o>>1)&3))*8 + j ][tap]
    int unit = (bid - 1032) * 256 + tid;        // < 294912
    int s = unit >> 11;
    int rem = unit & 2047;
    int o = rem >> 2, sp = rem & 3;
    int tap = s >> 4, cc = s & 15;
    int i0 = cc * 32 + ((sp ^ ((o >> 1) & 3)) << 3);
    const float* src = cw + ((size_t)o * 512 + i0) * 9 + tap;
    short8v v;
    #pragma unroll
    for (int j = 0; j < 8; ++j) v[j] = f2bf(src[j * 9]);
    *(short8v*)(wpk + (size_t)unit * 8) = v;
  }
}

// ---------------- pre2: demod (blk 0..1023) + upsample (1024..1551) ---------
__global__ void k_pre2(const float* __restrict__ wsq, const float* __restrict__ style,
                       const float* __restrict__ x, float* __restrict__ demod,
                       short* __restrict__ xm) {
  __shared__ float xt[2][64][33];
  int bid = blockIdx.x, tid = threadIdx.x;
  if (bid < 1024) {
    int wid = tid >> 6, lane = tid & 63;
    int idx = bid * 4 + wid;                    // (b,o)
    int b = idx >> 9, o = idx & 511;
    const float* wr = wsq + (size_t)o * 512;
    const float* ss = style + b * 512;
    float sum = 0.f;
    #pragma unroll
    for (int k = 0; k < 8; ++k) {
      int i = k * 64 + lane;
      float s = ss[i];
      sum += wr[i] * s * s;
    }
    #pragma unroll
    for (int off = 32; off; off >>= 1) sum += __shfl_down(sum, off);
    if (lane == 0) demod[b * 512 + o] = rsqrtf(sum + 1e-8f);
    return;
  }
  // ---- original upsample body ----
  int bb = bid - 1024;
  int b = bb / 66, hp = bb % 66;
  short* xmp = xm + ((size_t)b * 66 + hp) * 66 * 512;
  if (hp == 0 || hp == 65) {
    short8v z = {0, 0, 0, 0, 0, 0, 0, 0};
    for (int u = tid; u < 66 * 512 / 8; u += 256) ((short8v*)xmp)[u] = z;
    return;
  }
  int h = hp - 1;
  int j0 = (h >> 1) - 1 + (h & 1);
  float fj = (h & 1) ? 0.25f : 0.75f;
  int j0c = j0 < 0 ? 0 : j0;
  int j1c = j0 + 1 > 31 ? 31 : j0 + 1;
  int ccc = tid & 63;
  int wsub = tid >> 6;
  for (int c0 = 0; c0 < 512; c0 += 64) {
    __syncthreads();
    #pragma unroll 4
    for (int k = 0; k < 16; ++k) {
      int idx = k * 256 + tid;
      int ii = idx & 31, cc = (idx >> 5) & 63, jj = idx >> 11;
      xt[jj][cc][ii] = x[(((size_t)b * 512 + c0 + cc) * 32 + (jj ? j1c : j0c)) * 32 + ii];
    }
    __syncthreads();
    float sstyle = style[b * 512 + c0 + ccc];
    #pragma unroll 4
    for (int wk = 0; wk < 16; ++wk) {
      int w = wk * 4 + wsub;
      int i0 = (w >> 1) - 1 + (w & 1);
      float fi = (w & 1) ? 0.25f : 0.75f;
      int i0c = i0 < 0 ? 0 : i0;
      int i1c = i0 + 1 > 31 ? 31 : i0 + 1;
      float v0 = xt[0][ccc][i0c] * (1.f - fi) + xt[0][ccc][i1c] * fi;
      float v1 = xt[1][ccc][i0c] * (1.f - fi) + xt[1][ccc][i1c] * fi;
      float v = (v0 * (1.f - fj) + v1 * fj) * sstyle;
      xmp[(size_t)(w + 1) * 512 + c0 + ccc] = f2bf(v);
    }
    if (wsub == 0) {
      xmp[c0 + ccc] = 0;
      xmp[(size_t)65 * 512 + c0 + ccc] = 0;
    }
  }
}

// ---------------- main conv: 2 blocks/CU, reg-staged xm, fused rgb ----------
// grid 512; T1 XCD swizzle: 4 coq blocks of one (hq,b) -> same XCD L2.
// wave: 128 cout (coq*128..) x row(hq*4+wsrow) x 64 w
__global__ __launch_bounds__(256, 2) void k_conv(
    const short* __restrict__ xm, const short* __restrict__ wpk,
    const float* __restrict__ demod, const float* __restrict__ convb,
    const float* __restrict__ nscal, const float* __restrict__ noise,
    const float* __restrict__ t, const float* __restrict__ prelu_a,
    const float* __restrict__ ow, float* __restrict__ part,
    float* __restrict__ y) {
  __shared__ char WTs[6][8192];    // ring: parity*3+slab, 128co x 4sp x 16B
  __shared__ char XMb[25344];      // single: [6 r][66 wp][4 slot]x16B

  int tid = threadIdx.x;
  int bid = blockIdx.x;
  int xcd = bid & 7, q = bid >> 3;
  int coq = q & 3, ghi = q >> 2;
  int g5 = ghi * 8 + xcd;          // 0..127
  int hq = g5 & 15, b = g5 >> 4;
  int wsrow = tid >> 6, lane = tid & 63;
  int l31 = lane & 31, lg = lane >> 5;

  const short* xb = xm + ((size_t)b * 66 + hq * 4) * 66 * 512;
  const short* wpkq = wpk + (size_t)coq * 128 * 32;   // this block's 128 couts
  int wb0 = (l31 << 6) + ((lg ^ ((l31 >> 1) & 3)) << 4);

  // xm staging units: u = k*256+tid (k=0..5) + tail u=1536+tid (tid<48)
  int off0, off1, off2, off3, off4, off5, off6;
  int d0, d1, d2, d3, d4, d5, d6;
  {
    int u, r, rem, wp, sp;
    u = tid;        r = u / 264; rem = u - r * 264; wp = rem >> 2; sp = rem & 3;
    off0 = (r * 66 + wp) * 512 + ((sp ^ ((wp >> 1) & 3)) << 3); d0 = u * 16;
    u = 256 + tid;  r = u / 264; rem = u - r * 264; wp = rem >> 2; sp = rem & 3;
    off1 = (r * 66 + wp) * 512 + ((sp ^ ((wp >> 1) & 3)) << 3); d1 = u * 16;
    u = 512 + tid;  r = u / 264; rem = u - r * 264; wp = rem >> 2; sp = rem & 3;
    off2 = (r * 66 + wp) * 512 + ((sp ^ ((wp >> 1) & 3)) << 3); d2 = u * 16;
    u = 768 + tid;  r = u / 264; rem = u - r * 264; wp = rem >> 2; sp = rem & 3;
    off3 = (r * 66 + wp) * 512 + ((sp ^ ((wp >> 1) & 3)) << 3); d3 = u * 16;
    u = 1024 + tid; r = u / 264; rem = u - r * 264; wp = rem >> 2; sp = rem & 3;
    off4 = (r * 66 + wp) * 512 + ((sp ^ ((wp >> 1) & 3)) << 3); d4 = u * 16;
    u = 1280 + tid; r = u / 264; rem = u - r * 264; wp = rem >> 2; sp = rem & 3;
    off5 = (r * 66 + wp) * 512 + ((sp ^ ((wp >> 1) & 3)) << 3); d5 = u * 16;
    u = 1536 + (tid & 63); if (u > 1583) u = 1583;   // only tid<48 uses it
    r = u / 264; rem = u - r * 264; wp = rem >> 2; sp = rem & 3;
    off6 = (r * 66 + wp) * 512 + ((sp ^ ((wp >> 1) & 3)) << 3); d6 = u * 16;
  }

  // ---- prologue: XM(cc0) + WT slabs for phase 0 (taps 0..2) ----
  gld16(xb + off0, XMb + d0);
  gld16(xb + off1, XMb + d1);
  gld16(xb + off2, XMb + d2);
  gld16(xb + off3, XMb + d3);
  gld16(xb + off4, XMb + d4);
  gld16(xb + off5, XMb + d5);
  if (tid < 48) gld16(xb + off6, XMb + d6);
  #pragma unroll
  for (int j = 0; j < 3; ++j) {
    const short* ws = wpkq + (size_t)(j * 16) * 16384;   // tap j, cc0
    gld16(ws + tid * 8, WTs[j] + tid * 16);
    gld16(ws + (256 + tid) * 8, WTs[j] + (256 + tid) * 16);
  }

  f32x16 zf = {0,0,0,0,0,0,0,0,0,0,0,0,0,0,0,0};
  f32x16 acc[4][2];
  #pragma unroll
  for (int i = 0; i < 4; ++i) { acc[i][0] = zf; acc[i][1] = zf; }

  asm volatile("s_waitcnt vmcnt(0)" ::: "memory");
  __builtin_amdgcn_s_barrier();
  __builtin_amdgcn_sched_barrier(0);

  short8v xr0, xr1, xr2, xr3, xr4, xr5, xr6;

  #pragma unroll 1
  for (int cc = 0; cc < 16; ++cc) {
    #pragma unroll
    for (int krow = 0; krow < 3; ++krow) {
      int g = cc * 3 + krow;
      const char* WTc = (const char*)WTs + (size_t)((g & 1) * 3) * 8192;
      char* WTn = (char*)WTs + (size_t)(((g + 1) & 1) * 3) * 8192;

      // A. stage next phase's 3 weight slabs (6 gld16, uniform)
      if (g < 47) {
        int nkrow = (krow < 2) ? krow + 1 : 0;
        int ncc = (krow < 2) ? cc : cc + 1;
        #pragma unroll
        for (int j = 0; j < 3; ++j) {
          const short* ws = wpkq + (size_t)((nkrow * 3 + j) * 16 + ncc) * 16384;
          gld16(ws + tid * 8, WTn + j * 8192 + tid * 16);
          gld16(ws + (256 + tid) * 8, WTn + j * 8192 + (256 + tid) * 16);
        }
      }
      // B. reg-load xm for cc+1 at krow2 (written at the cc boundary)
      if (krow == 2 && cc < 15) {
        const short* xs = xb + (cc + 1) * 32;
        xr0 = *(const short8v*)(xs + off0);
        xr1 = *(const short8v*)(xs + off1);
        xr2 = *(const short8v*)(xs + off2);
        xr3 = *(const short8v*)(xs + off3);
        xr4 = *(const short8v*)(xs + off4);
        xr5 = *(const short8v*)(xs + off5);
        if (tid < 48) xr6 = *(const short8v*)(xs + off6);
      }

      // C. compute 3 taps (no barriers between — compiler interleaves)
      #pragma unroll
      for (int j = 0; j < 3; ++j) {
        const char* Wp = WTc + j * 8192;
        bf16x8 wf0[4], wf1[4];
        #pragma unroll
        for (int cf = 0; cf < 4; ++cf) {
          wf0[cf] = *(const bf16x8*)(Wp + (wb0 + cf * 2048));
          wf1[cf] = *(const bf16x8*)(Wp + ((wb0 + cf * 2048) ^ 32));
        }
        int a = l31 + j;            // kw = j
        int xo = ((wsrow + krow) * 66 + a) * 64 + ((lg ^ ((a >> 1) & 3)) << 4);
        bf16x8 xf00 = *(const bf16x8*)(XMb + xo);
        bf16x8 xf01 = *(const bf16x8*)(XMb + xo + 2048);
        bf16x8 xf10 = *(const bf16x8*)(XMb + (xo ^ 32));
        bf16x8 xf11 = *(const bf16x8*)(XMb + ((xo ^ 32) + 2048));

        #pragma unroll
        for (int cf = 0; cf < 4; ++cf) {
          acc[cf][0] = __builtin_amdgcn_mfma_f32_32x32x16_bf16(wf0[cf], xf00, acc[cf][0], 0, 0, 0);
          acc[cf][1] = __builtin_amdgcn_mfma_f32_32x32x16_bf16(wf0[cf], xf01, acc[cf][1], 0, 0, 0);
        }
        #pragma unroll
        for (int cf = 0; cf < 4; ++cf) {
          acc[cf][0] = __builtin_amdgcn_mfma_f32_32x32x16_bf16(wf1[cf], xf10, acc[cf][0], 0, 0, 0);
          acc[cf][1] = __builtin_amdgcn_mfma_f32_32x32x16_bf16(wf1[cf], xf11, acc[cf][1], 0, 0, 0);
        }
      }

      // D. phase end
      if (krow < 2) {
        asm volatile("s_waitcnt vmcnt(0)" ::: "memory");
        __builtin_amdgcn_s_barrier();
        __builtin_amdgcn_sched_barrier(0);
      } else {
        // cc boundary: all waves done reading XM; swap contents in place
        asm volatile("s_waitcnt vmcnt(0) lgkmcnt(0)" ::: "memory");
        __builtin_amdgcn_s_barrier();
        if (cc < 15) {
          *(short8v*)(XMb + d0) = xr0;
          *(short8v*)(XMb + d1) = xr1;
          *(short8v*)(XMb + d2) = xr2;
          *(short8v*)(XMb + d3) = xr3;
          *(short8v*)(XMb + d4) = xr4;
          *(short8v*)(XMb + d5) = xr5;
          if (tid < 48) *(short8v*)(XMb + d6) = xr6;
        }
        asm volatile("s_waitcnt lgkmcnt(0)" ::: "memory");
        __builtin_amdgcn_s_barrier();
        __builtin_amdgcn_sched_barrier(0);
      }
    }
  }

  // ---- epilogue: demod + bias + noise + prelu + (y+t)/sqrt2 + rgb partials --
  float pa = prelu_a[0];
  const float inv_r2 = 1.0f / 1.41421f;
  int h = hq * 4 + wsrow;
  float nz0 = noise[((size_t)b * 64 + h) * 64 + l31];
  float nz1 = noise[((size_t)b * 64 + h) * 64 + 32 + l31];
  float pr[3][2] = {{0.f, 0.f}, {0.f, 0.f}, {0.f, 0.f}};   // [c][sf]
  #pragma unroll
  for (int cf = 0; cf < 4; ++cf) {
    #pragma unroll
    for (int reg = 0; reg < 16; ++reg) {
      int orow = (reg & 3) + 8 * (reg >> 2) + 4 * lg;
      int o = coq * 128 + cf * 32 + orow;
      float dm = demod[b * 512 + o];
      float cb = convb[o];
      float ns = nscal[o];
      float w0 = ow[o], w1 = ow[512 + o], w2 = ow[1024 + o];
      #pragma unroll
      for (int sf = 0; sf < 2; ++sf) {
        int w = sf * 32 + l31;
        float v = acc[cf][sf][reg];
        v = v * dm + cb + ns * (sf ? nz1 : nz0);
        v = (v >= 0.f) ? v : pa * v;
        size_t oi = (((size_t)b * 512 + o) * 64 + h) * 64 + w;
        v = (v + t[oi]) * inv_r2;
        y[oi] = v;
        pr[0][sf] += v * w0;
        pr[1][sf] += v * w1;
        pr[2][sf] += v * w2;
      }
    }
  }
  #pragma unroll
  for (int c = 0; c < 3; ++c) {
    #pragma unroll
    for (int sf = 0; sf < 2; ++sf)
      pr[c][sf] += __shfl_down(pr[c][sf], 32);
  }
  if (lane < 32) {
    int slice = coq;
    float* pp = part + (((size_t)(slice * 8 + b) * 3) * 64 + h) * 64;
    #pragma unroll
    for (int c = 0; c < 3; ++c) {
      #pragma unroll
      for (int sf = 0; sf < 2; ++sf)
        pp[(size_t)c * 4096 + sf * 32 + l31] = pr[c][sf];
    }
  }
}

// ---------------- rgb finish: sum 4 slices + scale + bias + clamp -----------
__global__ void k_rgbfin(const float* __restrict__ part, const float* __restrict__ ob,
                         float* __restrict__ out) {
  int idx = blockIdx.x * 256 + threadIdx.x;   // over [b][3][64][64] = 98304
  int c = (idx / 4096) % 3;
  float s = part[idx] + part[98304 + idx] + part[196608 + idx] + part[294912 + idx];
  s = s * 0.0625f + ob[c];
  s = fminf(fmaxf(s, 0.f), 1.f);
  out[idx] = s;
}

extern "C" void kernel_launch(void* const* d_in, const int* in_sizes, int n_in,
                              void* d_out, int out_size, void* d_ws, size_t ws_size,
                              hipStream_t stream) {
  const float* x     = (const float*)d_in[0];
  const float* sb    = (const float*)d_in[1];
  const float* noise = (const float*)d_in[2];
  const float* t     = (const float*)d_in[3];
  const float* aw    = (const float*)d_in[4];
  const float* ab    = (const float*)d_in[5];
  const float* cw    = (const float*)d_in[6];
  const float* cb    = (const float*)d_in[7];
  const float* pa    = (const float*)d_in[8];
  const float* ns    = (const float*)d_in[9];
  const float* ow    = (const float*)d_in[10];
  const float* ob    = (const float*)d_in[11];
  char* ws = (char*)d_ws;
  float* style = (float*)(ws + WS_STYLE);
  float* demod = (float*)(ws + WS_DEMOD);
  float* wsq   = (float*)(ws + WS_WSQ);
  short* wpk   = (short*)(ws + WS_WPACK);
  short* xmw   = (short*)(ws + WS_XM);
  float* part  = (float*)(ws + WS_PART);
  float* y   = (float*)d_out;
  float* out = y + 16777216;

  k_pre1<<<2184, 256, 0, stream>>>(sb, aw, ab, cw, style, wsq, wpk);
  k_pre2<<<1552, 256, 0, stream>>>(wsq, style, x, demod, xmw);
  k_conv<<<512, 256, 0, stream>>>(xmw, wpk, demod, cb, ns, noise, t, pa, ow, part, y);
  k_rgbfin<<<384, 256, 0, stream>>>(part, ob, out);
}